// Round 1
// baseline (48.476 us; speedup 1.0000x reference)
//
#include <hip/hip_runtime.h>

// Problem: pred (1,2,4096,4096) f32, label (1,4096,4096) i32.
// Reference: pm = argmax_c pred  (== pred[1] > pred[0], argmax tie-break -> strict >)
//            w  = 3 if (pm!=lb && lb==1); 1 if (pm!=lb && lb==0); else 0
//            out = mean(w)  -> scalar f32.
// Memory-bound streaming reduction: 192 MiB in, 4 B out.

__global__ void zero_acc_kernel(unsigned int* acc) {
    if (threadIdx.x == 0 && blockIdx.x == 0) *acc = 0u;
}

__global__ __launch_bounds__(256) void loss_reduce_kernel(
        const float* __restrict__ pred,
        const int* __restrict__ label,
        unsigned int* __restrict__ acc,
        int n) {
    const float4* __restrict__ p0 = (const float4*)pred;        // class 0 plane
    const float4* __restrict__ p1 = (const float4*)(pred + n);  // class 1 plane
    const int4*   __restrict__ lb = (const int4*)label;

    const int nvec   = n >> 2;
    const int stride = gridDim.x * blockDim.x;
    unsigned int local = 0;

    for (int i = blockIdx.x * blockDim.x + threadIdx.x; i < nvec; i += stride) {
        float4 a = p0[i];
        float4 b = p1[i];
        int4   l = lb[i];
        // pm = 1 iff pred1 > pred0 (strict; argmax picks first index on tie)
        {
            int pm = (b.x > a.x) ? 1 : 0;
            if (pm != l.x) local += (l.x == 1) ? 3u : ((l.x == 0) ? 1u : 0u);
        }
        {
            int pm = (b.y > a.y) ? 1 : 0;
            if (pm != l.y) local += (l.y == 1) ? 3u : ((l.y == 0) ? 1u : 0u);
        }
        {
            int pm = (b.z > a.z) ? 1 : 0;
            if (pm != l.z) local += (l.z == 1) ? 3u : ((l.z == 0) ? 1u : 0u);
        }
        {
            int pm = (b.w > a.w) ? 1 : 0;
            if (pm != l.w) local += (l.w == 1) ? 3u : ((l.w == 0) ? 1u : 0u);
        }
    }

    // wave64 reduction
    #pragma unroll
    for (int off = 32; off > 0; off >>= 1)
        local += __shfl_down(local, off, 64);

    // block reduction via LDS (256 threads = 4 waves)
    __shared__ unsigned int wsum[4];
    const int lane = threadIdx.x & 63;
    const int wid  = threadIdx.x >> 6;
    if (lane == 0) wsum[wid] = local;
    __syncthreads();
    if (threadIdx.x == 0) {
        unsigned int s = wsum[0] + wsum[1] + wsum[2] + wsum[3];
        atomicAdd(acc, s);
    }
}

__global__ void finalize_kernel(const unsigned int* __restrict__ acc,
                                float* __restrict__ out, int n) {
    if (threadIdx.x == 0 && blockIdx.x == 0) {
        out[0] = (float)((double)(*acc) / (double)n);
    }
}

extern "C" void kernel_launch(void* const* d_in, const int* in_sizes, int n_in,
                              void* d_out, int out_size, void* d_ws, size_t ws_size,
                              hipStream_t stream) {
    const float* pred  = (const float*)d_in[0];
    const int*   label = (const int*)d_in[1];
    float*       out   = (float*)d_out;
    unsigned int* acc  = (unsigned int*)d_ws;
    const int n = in_sizes[1];  // 4096*4096 pixels

    zero_acc_kernel<<<1, 64, 0, stream>>>(acc);

    const int block = 256;
    const int grid  = 2048;  // 256 CUs x 8 blocks, grid-stride covers the rest
    loss_reduce_kernel<<<grid, block, 0, stream>>>(pred, label, acc, n);

    finalize_kernel<<<1, 64, 0, stream>>>(acc, out, n);
}